// Round 10
// baseline (188.050 us; speedup 1.0000x reference)
//
#include <hip/hip_runtime.h>
#include <stdint.h>

typedef __attribute__((ext_vector_type(8))) short short8;
typedef __attribute__((ext_vector_type(4))) short bf16x4;
typedef __attribute__((ext_vector_type(4))) float f32x4;

#define MFMA32(a, b, c) __builtin_amdgcn_mfma_f32_16x16x32_bf16((a), (b), (c), 0, 0, 0)

__device__ __forceinline__ uint16_t f32_to_bf16(float f) {
  union { float f; uint32_t u; } v; v.f = f;
  uint32_t u = v.u;
  u += 0x7FFFu + ((u >> 16) & 1u);   // RTNE
  return (uint16_t)(u >> 16);
}
__device__ __forceinline__ uint16_t f32_to_bf16_fast(float f) {
  union { float f; uint32_t u; } v; v.f = f;
  return (uint16_t)((v.u + 0x8000u) >> 16);   // round-half-up (P only)
}

__device__ __forceinline__ void load_lds16(const uint16_t* g, uint16_t* l) {
  __builtin_amdgcn_global_load_lds(
      (const __attribute__((address_space(1))) uint32_t*)g,
      (__attribute__((address_space(3))) uint32_t*)l, 16, 0, 0);
}

// ---------------- fused f32 -> bf16 conversion (x, Wqkv, Wout) ----------------
__global__ __launch_bounds__(256) void cvt3_kernel(
    const float* __restrict__ x, const float* __restrict__ w1,
    const float* __restrict__ w2, uint16_t* __restrict__ xb,
    uint16_t* __restrict__ w1b, uint16_t* __restrict__ w2b) {
  const int i = blockIdx.x * 256 + threadIdx.x;  // 2,097,152 float4 total
  const float4* src;
  ushort4* dst;
  int off;
  if (i < 1048576) { src = (const float4*)x;  dst = (ushort4*)xb;  off = i; }
  else if (i < 1835008) { src = (const float4*)w1; dst = (ushort4*)w1b; off = i - 1048576; }
  else { src = (const float4*)w2; dst = (ushort4*)w2b; off = i - 1835008; }
  const float4 v = src[off];
  ushort4 o;
  o.x = f32_to_bf16(v.x);
  o.y = f32_to_bf16(v.y);
  o.z = f32_to_bf16(v.z);
  o.w = f32_to_bf16(v.w);
  dst[off] = o;
}

// ---------------- QKV GEMM: 128x128 tile, BK=64, single-buffer serial (R7, proven) ----------------
// R10 epilogue change (attribution: gemm_qkv = 50us at MfmaUtil 18.6, ~1.7x the
// m97-reference time for this loop -> suspect the 64-scattered-stores epilogue):
//  - Q,K: PLAIN coalesced row-major stores into packed qkv[4096][3072] (like the
//    proven gemm_out epilogue). attn rebuilds the identical LDS frag layout via
//    per-lane global_load_lds source addresses (m173 pattern) -- 16B-contiguous
//    in row-major, verified: frag off wave*1024+c*512+lane*8 <-> row=t*64+
//    wave*16+l16, col=1024+h*64+c*32+quad*8. Softmax scale moves to attn (f32).
//  - V: keeps the sigma scatter (its frag k-axis spans non-contiguous rows; no
//    16B-contiguous row-major source exists).
__global__ __launch_bounds__(256) void gemm_qkv_kernel(
    const uint16_t* __restrict__ A, const uint16_t* __restrict__ Bt,
    uint16_t* __restrict__ qkv, uint16_t* __restrict__ Vh) {
  __shared__ __align__(16) uint16_t As[128 * 64];   // 16 KB
  __shared__ __align__(16) uint16_t Bs[128 * 64];   // 16 KB
  const int tid = threadIdx.x;
  const int wave = tid >> 6;
  const int lane = tid & 63;
  const int quad = lane >> 4;
  const int l16 = lane & 15;
  const int row0 = blockIdx.x * 128;
  const int col0 = blockIdx.y * 128;
  const int wm = (wave >> 1) * 64;
  const int wn = (wave & 1) * 64;
  const int K = 1024;

  f32x4 acc[4][4];
#pragma unroll
  for (int a = 0; a < 4; ++a)
#pragma unroll
    for (int b = 0; b < 4; ++b) acc[a][b] = (f32x4){0.f, 0.f, 0.f, 0.f};

  // staging: source chunk pre-swizzled (T2 write side); read swizzle cancels it.
  const int swz8 = ((lane & 7) ^ ((lane >> 3) & 7)) * 8;
  const uint16_t* gA = A + (size_t)(row0 + wave * 32 + (lane >> 3)) * K + swz8;
  const uint16_t* gB = Bt + (size_t)(col0 + wave * 32 + (lane >> 3)) * K + swz8;

  for (int k0 = 0; k0 < K; k0 += 64) {
#pragma unroll
    for (int s = 0; s < 4; ++s) {
      load_lds16(gA + (size_t)s * 8 * K + k0, &As[(wave * 32 + s * 8) * 64]);
      load_lds16(gB + (size_t)s * 8 * K + k0, &Bs[(wave * 32 + s * 8) * 64]);
    }
    __syncthreads();
#pragma unroll
    for (int ks = 0; ks < 2; ++ks) {
      const int cswz = (((ks * 4 + quad) ^ (l16 & 7)) * 8);
      short8 af[4], bf[4];
#pragma unroll
      for (int mt = 0; mt < 4; ++mt)
        af[mt] = *(const short8*)&As[(wm + mt * 16 + l16) * 64 + cswz];
#pragma unroll
      for (int nt = 0; nt < 4; ++nt)
        bf[nt] = *(const short8*)&Bs[(wn + nt * 16 + l16) * 64 + cswz];
#pragma unroll
      for (int mt = 0; mt < 4; ++mt)
#pragma unroll
        for (int nt = 0; nt < 4; ++nt)
          acc[mt][nt] = MFMA32(af[mt], bf[nt], acc[mt][nt]);
    }
    __syncthreads();
  }

  // epilogue
#pragma unroll
  for (int mt = 0; mt < 4; ++mt) {
#pragma unroll
    for (int nt = 0; nt < 4; ++nt) {
      const int col = col0 + wn + nt * 16 + l16;
      const int which = col >> 10;          // 0=q 1=k 2=v (block-uniform)
#pragma unroll
      for (int r = 0; r < 4; ++r) {
        const int row = row0 + wm + mt * 16 + quad * 4 + r;
        const float val = acc[mt][nt][r];
        if (which < 2) {
          // Q,K: plain coalesced row-major store (raw, unscaled)
          qkv[(size_t)row * 3072 + col] = f32_to_bf16(val);
        } else {
          const int hc = (col & 1023) >> 6;
          const int d = col & 63;
          const int b = row >> 11;
          const int nn = row & 2047;
          const size_t hb = (size_t)(b * 16 + hc) * 131072;
          const uint16_t bv = f32_to_bf16(val);
          // V: 16x16x32 B-frag, sigma-permuted j (unchanged from R9)
          const int jt = nn >> 6, jp = nn & 63;
          const int st2 = jp >> 5, j32 = jp & 31;
          const int qv = (j32 >> 2) & 3, e = (j32 >> 4) * 4 + (j32 & 3);
          const int dt = d >> 4, d16 = d & 15;
          Vh[hb + jt * 4096 + (st2 * 4 + dt) * 512 + (qv * 16 + d16) * 8 + e] = bv;
        }
      }
    }
  }
}

// ---------------- output-proj GEMM: 128x64 tile, BK=64, single-buffer serial (R7, proven) ----------------
__global__ __launch_bounds__(256) void gemm_out_kernel(
    const uint16_t* __restrict__ A, const uint16_t* __restrict__ Bt,
    float* __restrict__ Cf, const float* __restrict__ bias) {
  __shared__ __align__(16) uint16_t As[128 * 64];   // 16 KB
  __shared__ __align__(16) uint16_t Bs[64 * 64];    // 8 KB
  const int tid = threadIdx.x;
  const int wave = tid >> 6;
  const int lane = tid & 63;
  const int quad = lane >> 4;
  const int l16 = lane & 15;
  const int row0 = blockIdx.x * 128;
  const int col0 = blockIdx.y * 64;
  const int wm = (wave >> 1) * 64;
  const int wn = (wave & 1) * 32;
  const int K = 1024;
  const int N = 1024;

  f32x4 acc[4][2];
#pragma unroll
  for (int a = 0; a < 4; ++a)
#pragma unroll
    for (int b = 0; b < 2; ++b) acc[a][b] = (f32x4){0.f, 0.f, 0.f, 0.f};

  const int swz8 = ((lane & 7) ^ ((lane >> 3) & 7)) * 8;
  const uint16_t* gA = A + (size_t)(row0 + wave * 32 + (lane >> 3)) * K + swz8;
  const uint16_t* gB = Bt + (size_t)(col0 + wave * 16 + (lane >> 3)) * K + swz8;

  for (int k0 = 0; k0 < K; k0 += 64) {
#pragma unroll
    for (int s = 0; s < 4; ++s)
      load_lds16(gA + (size_t)s * 8 * K + k0, &As[(wave * 32 + s * 8) * 64]);
#pragma unroll
    for (int s = 0; s < 2; ++s)
      load_lds16(gB + (size_t)s * 8 * K + k0, &Bs[(wave * 16 + s * 8) * 64]);
    __syncthreads();
#pragma unroll
    for (int ks = 0; ks < 2; ++ks) {
      const int cswz = (((ks * 4 + quad) ^ (l16 & 7)) * 8);
      short8 af[4], bf[2];
#pragma unroll
      for (int mt = 0; mt < 4; ++mt)
        af[mt] = *(const short8*)&As[(wm + mt * 16 + l16) * 64 + cswz];
#pragma unroll
      for (int nt = 0; nt < 2; ++nt)
        bf[nt] = *(const short8*)&Bs[(wn + nt * 16 + l16) * 64 + cswz];
#pragma unroll
      for (int mt = 0; mt < 4; ++mt)
#pragma unroll
        for (int nt = 0; nt < 2; ++nt)
          acc[mt][nt] = MFMA32(af[mt], bf[nt], acc[mt][nt]);
    }
    __syncthreads();
  }

#pragma unroll
  for (int mt = 0; mt < 4; ++mt) {
#pragma unroll
    for (int nt = 0; nt < 2; ++nt) {
      const int col = col0 + wn + nt * 16 + l16;
#pragma unroll
      for (int r = 0; r < 4; ++r) {
        const int row = row0 + wm + mt * 16 + quad * 4 + r;
        Cf[(size_t)row * N + col] = acc[mt][nt][r] + bias[col];
      }
    }
  }
}

// ---------------- flash attention, LDS-shared KV, 64-row blocks, MFMA32 PV ----------------
// R10: Q and K now read from the PACKED row-major qkv buffer.
//  - Q frags: per-lane 16B loads, stride 3072 (raw Q; softmax scale applied in
//    f32 to s before exp2: exp2(s * 0.125*log2e)).
//  - K staging: per-lane global_load_lds SOURCE addresses rebuild the exact
//    same LDS frag layout as before (content byte-identical -> compute core
//    untouched). V unchanged (sigma frag buffer).
// Head->XCD swizzle kept (K/V L2-resident, FETCH 12 MB measured in R8).
__global__ __launch_bounds__(256, 4) void attn_kernel(
    const uint16_t* __restrict__ qkv, const uint16_t* __restrict__ Vh,
    uint16_t* __restrict__ out) {
  __shared__ __align__(16) uint16_t Ks[2][4096];
  __shared__ __align__(16) uint16_t Vs[2][4096];
  const int tid = threadIdx.x;
  const int wave = tid >> 6;
  const int lane = tid & 63;
  const int quad = lane >> 4;
  const int l16 = lane & 15;
  const int bx = blockIdx.x;
  // bx = g*8 + xcd ; g = it + 32*hhi + 64*ib ; h = hhi*8 + xcd
  const int xcd = bx & 7;
  const int g = bx >> 3;
  const int it = g & 31;            // 32 i-tiles of 64 rows
  const int h = ((g >> 5) & 1) * 8 + xcd;
  const int ib = g >> 6;
  const int i0 = it * 64 + wave * 16;
  const float SC = 0.1803368801111244f;   // 0.125 * log2(e)

  // Q fragments (B-operand of S^T MFMA): lane l16 = q-row, k = quad*8+e
  short8 qf[2];
#pragma unroll
  for (int kc = 0; kc < 2; ++kc)
    qf[kc] = *(const short8*)(qkv + (size_t)(ib * 2048 + i0 + l16) * 3072 +
                              h * 64 + kc * 32 + quad * 8);

  f32x4 o[4], o4;
  o4 = (f32x4){0.f, 0.f, 0.f, 0.f};
#pragma unroll
  for (int t = 0; t < 4; ++t) o[t] = (f32x4){0.f, 0.f, 0.f, 0.f};

  const short8 ones8 = {(short)0x3F80, (short)0x3F80, (short)0x3F80, (short)0x3F80,
                        (short)0x3F80, (short)0x3F80, (short)0x3F80, (short)0x3F80};

  // K staging source (per-lane, row-major packed):
  // frag off wave*1024 + c*512 + lane*8 <-> row = t*64 + wave*16 + l16,
  //                                         col = 1024 + h*64 + c*32 + quad*8
  const uint16_t* gK = qkv + (size_t)(ib * 2048 + wave * 16 + l16) * 3072 +
                       1024 + h * 64 + quad * 8;
  // V staging source (frag-order buffer, as before)
  const uint16_t* gV = Vh + (size_t)(ib * 16 + h) * 131072 + wave * 1024 + lane * 8;
  const int so = wave * 1024;

  // prologue: stage tile 0 into buf 0
  load_lds16(gK, &Ks[0][so]);
  load_lds16(gK + 32, &Ks[0][so + 512]);
  load_lds16(gV, &Vs[0][so]);
  load_lds16(gV + 512, &Vs[0][so + 512]);
  __syncthreads();

#pragma unroll 2
  for (int t = 0; t < 32; ++t) {
    const int cur = t & 1;
    // stage tile t+1 into the other buffer (hidden under this tile's compute)
    if (t < 31) {
      const size_t koff = (size_t)(t + 1) * (64 * 3072);
      const size_t voff = (size_t)(t + 1) * 4096;
      load_lds16(gK + koff, &Ks[cur ^ 1][so]);
      load_lds16(gK + koff + 32, &Ks[cur ^ 1][so + 512]);
      load_lds16(gV + voff, &Vs[cur ^ 1][so]);
      load_lds16(gV + voff + 512, &Vs[cur ^ 1][so + 512]);
    }

    // K frags from LDS (same frag order as before)
    short8 kf[8];
#pragma unroll
    for (int i = 0; i < 8; ++i) kf[i] = *(const short8*)&Ks[cur][i * 512 + lane * 8];

    // S^T = K . Q^T : lane holds q-row l16, j = st*16 + quad*4 + r
    f32x4 s[4];
#pragma unroll
    for (int st = 0; st < 4; ++st) {
      f32x4 sc = (f32x4){0.f, 0.f, 0.f, 0.f};
      sc = MFMA32(kf[st * 2 + 0], qf[0], sc);
      sc = MFMA32(kf[st * 2 + 1], qf[1], sc);
      s[st] = sc;
    }

    // V frags (sigma-permuted B-frags; i = st2*4 + dt)
    short8 v8[8];
#pragma unroll
    for (int i = 0; i < 8; ++i) v8[i] = *(const short8*)&Vs[cur][i * 512 + lane * 8];

    // P = exp2(s*SC), packed straight into sigma-ordered x32 A-frags
    short8 p8[2];
#pragma unroll
    for (int st2 = 0; st2 < 2; ++st2) {
      short8 p;
#pragma unroll
      for (int hh = 0; hh < 2; ++hh)
#pragma unroll
        for (int r = 0; r < 4; ++r)
          p[hh * 4 + r] = (short)f32_to_bf16_fast(
              __builtin_amdgcn_exp2f(s[st2 * 2 + hh][r] * SC));
      p8[st2] = p;
    }

    // O += P V via MFMA32 (8 PV + 2 row-sum per tile)
#pragma unroll
    for (int st2 = 0; st2 < 2; ++st2) {
      o4 = MFMA32(p8[st2], ones8, o4);
#pragma unroll
      for (int dt = 0; dt < 4; ++dt)
        o[dt] = MFMA32(p8[st2], v8[st2 * 4 + dt], o[dt]);
    }

    __syncthreads();
  }

  // epilogue: O /= l, store bf16 [B*2048][1024]
#pragma unroll
  for (int r = 0; r < 4; ++r) {
    const float inv = 1.0f / o4[r];
    const int row = i0 + quad * 4 + r;
    const size_t obase = (size_t)(ib * 2048 + row) * 1024 + h * 64;
#pragma unroll
    for (int tt = 0; tt < 4; ++tt)
      out[obase + tt * 16 + l16] = f32_to_bf16(o[tt][r] * inv);
  }
}

// ---------------- launch ----------------
extern "C" void kernel_launch(void* const* d_in, const int* in_sizes, int n_in,
                              void* d_out, int out_size, void* d_ws, size_t ws_size,
                              hipStream_t stream) {
  const float* x = (const float*)d_in[0];     // [2,2048,1024]
  const float* Wqkv = (const float*)d_in[1];  // [3072,1024]
  const float* Wout = (const float*)d_in[2];  // [1024,1024]
  const float* bout = (const float*)d_in[3];  // [1024]

  uint16_t* xb = (uint16_t*)d_ws;                       // 4096*1024
  uint16_t* wqkvb = xb + (size_t)4096 * 1024;           // 3072*1024
  uint16_t* woutb = wqkvb + (size_t)3072 * 1024;        // 1024*1024
  uint16_t* qkvb = woutb + (size_t)1024 * 1024;         // 4096*3072 packed q|k|v
  uint16_t* vh = qkvb + (size_t)4096 * 3072;            // 32 heads * 131072 (sigma frags)
  uint16_t* attnb = vh + (size_t)32 * 131072;           // 4096*1024

  cvt3_kernel<<<8192, 256, 0, stream>>>(x, Wqkv, Wout, xb, wqkvb, woutb);

  gemm_qkv_kernel<<<dim3(4096 / 128, 3072 / 128), 256, 0, stream>>>(
      xb, wqkvb, qkvb, vh);

  attn_kernel<<<1024, 256, 0, stream>>>(qkvb, vh, attnb);

  gemm_out_kernel<<<dim3(4096 / 128, 1024 / 64), 256, 0, stream>>>(
      attnb, woutb, (float*)d_out, bout);
}

// Round 11
// 180.487 us; speedup vs baseline: 1.0419x; 1.0419x over previous
//
#include <hip/hip_runtime.h>
#include <stdint.h>

typedef __attribute__((ext_vector_type(8))) short short8;
typedef __attribute__((ext_vector_type(4))) short bf16x4;
typedef __attribute__((ext_vector_type(4))) float f32x4;

#define MFMA32(a, b, c) __builtin_amdgcn_mfma_f32_16x16x32_bf16((a), (b), (c), 0, 0, 0)

__device__ __forceinline__ uint16_t f32_to_bf16(float f) {
  union { float f; uint32_t u; } v; v.f = f;
  uint32_t u = v.u;
  u += 0x7FFFu + ((u >> 16) & 1u);   // RTNE
  return (uint16_t)(u >> 16);
}
__device__ __forceinline__ uint16_t f32_to_bf16_fast(float f) {
  union { float f; uint32_t u; } v; v.f = f;
  return (uint16_t)((v.u + 0x8000u) >> 16);   // round-half-up (P only)
}

__device__ __forceinline__ void load_lds16(const uint16_t* g, uint16_t* l) {
  __builtin_amdgcn_global_load_lds(
      (const __attribute__((address_space(1))) uint32_t*)g,
      (__attribute__((address_space(3))) uint32_t*)l, 16, 0, 0);
}

// ---------------- fused f32 -> bf16 conversion (x, Wqkv, Wout) ----------------
__global__ __launch_bounds__(256) void cvt3_kernel(
    const float* __restrict__ x, const float* __restrict__ w1,
    const float* __restrict__ w2, uint16_t* __restrict__ xb,
    uint16_t* __restrict__ w1b, uint16_t* __restrict__ w2b) {
  const int i = blockIdx.x * 256 + threadIdx.x;  // 2,097,152 float4 total
  const float4* src;
  ushort4* dst;
  int off;
  if (i < 1048576) { src = (const float4*)x;  dst = (ushort4*)xb;  off = i; }
  else if (i < 1835008) { src = (const float4*)w1; dst = (ushort4*)w1b; off = i - 1048576; }
  else { src = (const float4*)w2; dst = (ushort4*)w2b; off = i - 1835008; }
  const float4 v = src[off];
  ushort4 o;
  o.x = f32_to_bf16(v.x);
  o.y = f32_to_bf16(v.y);
  o.z = f32_to_bf16(v.z);
  o.w = f32_to_bf16(v.w);
  dst[off] = o;
}

// ---------------- QKV GEMM: 128x64 tile, BK=64, single-buffer serial ----------------
// R10 reverted (row-major K staging destroyed attn coalescing: 64 cache-line
// segments per global_load_lds vs 1KB contiguous; scatter belongs on the STORE
// side, never the staged-load side). R11 change vs R9: tile 128x128 -> 128x64.
// Mechanism: R9 counters (MfmaUtil 18.6 + VALUBusy 17.3, both <20%, conflicts 0,
// HBM 14%) = latency-bound with only 3 blocks/CU of inter-block overlap on a
// serial stage->drain->compute loop. 128x64: grid 1536 -> 6 blocks/CU
// (LDS 24KB, acc 32 VGPR) -- same lever that fixed gemm_out in R7. MFMA totals
// unchanged; A-panel L2 re-reads double (trivial, L2-resident).
__global__ __launch_bounds__(256) void gemm_qkv_kernel(
    const uint16_t* __restrict__ A, const uint16_t* __restrict__ Bt,
    uint16_t* __restrict__ Qh, uint16_t* __restrict__ Kh, uint16_t* __restrict__ Vh) {
  __shared__ __align__(16) uint16_t As[128 * 64];   // 16 KB
  __shared__ __align__(16) uint16_t Bs[64 * 64];    // 8 KB
  const int tid = threadIdx.x;
  const int wave = tid >> 6;
  const int lane = tid & 63;
  const int quad = lane >> 4;
  const int l16 = lane & 15;
  const int row0 = blockIdx.x * 128;
  const int col0 = blockIdx.y * 64;
  const int wm = (wave >> 1) * 64;
  const int wn = (wave & 1) * 32;
  const int K = 1024;

  f32x4 acc[4][2];
#pragma unroll
  for (int a = 0; a < 4; ++a)
#pragma unroll
    for (int b = 0; b < 2; ++b) acc[a][b] = (f32x4){0.f, 0.f, 0.f, 0.f};

  // staging: source chunk pre-swizzled (T2 write side); read swizzle cancels it.
  const int swz8 = ((lane & 7) ^ ((lane >> 3) & 7)) * 8;
  const uint16_t* gA = A + (size_t)(row0 + wave * 32 + (lane >> 3)) * K + swz8;
  const uint16_t* gB = Bt + (size_t)(col0 + wave * 16 + (lane >> 3)) * K + swz8;

  for (int k0 = 0; k0 < K; k0 += 64) {
#pragma unroll
    for (int s = 0; s < 4; ++s)
      load_lds16(gA + (size_t)s * 8 * K + k0, &As[(wave * 32 + s * 8) * 64]);
#pragma unroll
    for (int s = 0; s < 2; ++s)
      load_lds16(gB + (size_t)s * 8 * K + k0, &Bs[(wave * 16 + s * 8) * 64]);
    __syncthreads();
#pragma unroll
    for (int ks = 0; ks < 2; ++ks) {
      const int cswz = (((ks * 4 + quad) ^ (l16 & 7)) * 8);
      short8 af[4], bf[2];
#pragma unroll
      for (int mt = 0; mt < 4; ++mt)
        af[mt] = *(const short8*)&As[(wm + mt * 16 + l16) * 64 + cswz];
#pragma unroll
      for (int nt = 0; nt < 2; ++nt)
        bf[nt] = *(const short8*)&Bs[(wn + nt * 16 + l16) * 64 + cswz];
#pragma unroll
      for (int mt = 0; mt < 4; ++mt)
#pragma unroll
        for (int nt = 0; nt < 2; ++nt)
          acc[mt][nt] = MFMA32(af[mt], bf[nt], acc[mt][nt]);
    }
    __syncthreads();
  }

  // epilogue: qkv swizzle (verbatim R9 formulas; nt range now 2)
#pragma unroll
  for (int mt = 0; mt < 4; ++mt) {
#pragma unroll
    for (int nt = 0; nt < 2; ++nt) {
      const int col = col0 + wn + nt * 16 + l16;
      const int which = col >> 10;          // 0=q 1=k 2=v (block-uniform, 1024%64==0)
      const int hc = (col & 1023) >> 6;
      const int d = col & 63;
#pragma unroll
      for (int r = 0; r < 4; ++r) {
        const int row = row0 + wm + mt * 16 + quad * 4 + r;
        const float val = acc[mt][nt][r];
        const int b = row >> 11;
        const int nn = row & 2047;
        const size_t hb = (size_t)(b * 16 + hc) * 131072;
        if (which == 0) {
          // fold softmax scale (1/8) and log2(e) into Q
          Qh[hb + (size_t)nn * 64 + d] = f32_to_bf16(val * 0.1803368801111244f);
        } else if (which == 1) {
          const uint16_t bv = f32_to_bf16(val);
          // K: 16x16x32 A-frag order [jt][st][kc][lane=qd*16+j16][e8]
          const int jt = nn >> 6, st = (nn >> 4) & 3, j16 = nn & 15;
          const int kc = d >> 5, qd = (d >> 3) & 3, e = d & 7;
          Kh[hb + jt * 4096 + st * 1024 + kc * 512 + (qd * 16 + j16) * 8 + e] = bv;
        } else {
          const uint16_t bv = f32_to_bf16(val);
          // V: 16x16x32 B-frag, sigma-permuted j (R9):
          const int jt = nn >> 6, jp = nn & 63;
          const int st2 = jp >> 5, j32 = jp & 31;
          const int qv = (j32 >> 2) & 3, e = (j32 >> 4) * 4 + (j32 & 3);
          const int dt = d >> 4, d16 = d & 15;
          Vh[hb + jt * 4096 + (st2 * 4 + dt) * 512 + (qv * 16 + d16) * 8 + e] = bv;
        }
      }
    }
  }
}

// ---------------- output-proj GEMM: 128x64 tile, BK=64, single-buffer serial (R7, proven) ----------------
__global__ __launch_bounds__(256) void gemm_out_kernel(
    const uint16_t* __restrict__ A, const uint16_t* __restrict__ Bt,
    float* __restrict__ Cf, const float* __restrict__ bias) {
  __shared__ __align__(16) uint16_t As[128 * 64];   // 16 KB
  __shared__ __align__(16) uint16_t Bs[64 * 64];    // 8 KB
  const int tid = threadIdx.x;
  const int wave = tid >> 6;
  const int lane = tid & 63;
  const int quad = lane >> 4;
  const int l16 = lane & 15;
  const int row0 = blockIdx.x * 128;
  const int col0 = blockIdx.y * 64;
  const int wm = (wave >> 1) * 64;
  const int wn = (wave & 1) * 32;
  const int K = 1024;
  const int N = 1024;

  f32x4 acc[4][2];
#pragma unroll
  for (int a = 0; a < 4; ++a)
#pragma unroll
    for (int b = 0; b < 2; ++b) acc[a][b] = (f32x4){0.f, 0.f, 0.f, 0.f};

  const int swz8 = ((lane & 7) ^ ((lane >> 3) & 7)) * 8;
  const uint16_t* gA = A + (size_t)(row0 + wave * 32 + (lane >> 3)) * K + swz8;
  const uint16_t* gB = Bt + (size_t)(col0 + wave * 16 + (lane >> 3)) * K + swz8;

  for (int k0 = 0; k0 < K; k0 += 64) {
#pragma unroll
    for (int s = 0; s < 4; ++s)
      load_lds16(gA + (size_t)s * 8 * K + k0, &As[(wave * 32 + s * 8) * 64]);
#pragma unroll
    for (int s = 0; s < 2; ++s)
      load_lds16(gB + (size_t)s * 8 * K + k0, &Bs[(wave * 16 + s * 8) * 64]);
    __syncthreads();
#pragma unroll
    for (int ks = 0; ks < 2; ++ks) {
      const int cswz = (((ks * 4 + quad) ^ (l16 & 7)) * 8);
      short8 af[4], bf[2];
#pragma unroll
      for (int mt = 0; mt < 4; ++mt)
        af[mt] = *(const short8*)&As[(wm + mt * 16 + l16) * 64 + cswz];
#pragma unroll
      for (int nt = 0; nt < 2; ++nt)
        bf[nt] = *(const short8*)&Bs[(wn + nt * 16 + l16) * 64 + cswz];
#pragma unroll
      for (int mt = 0; mt < 4; ++mt)
#pragma unroll
        for (int nt = 0; nt < 2; ++nt)
          acc[mt][nt] = MFMA32(af[mt], bf[nt], acc[mt][nt]);
    }
    __syncthreads();
  }

#pragma unroll
  for (int mt = 0; mt < 4; ++mt) {
#pragma unroll
    for (int nt = 0; nt < 2; ++nt) {
      const int col = col0 + wn + nt * 16 + l16;
#pragma unroll
      for (int r = 0; r < 4; ++r) {
        const int row = row0 + wm + mt * 16 + quad * 4 + r;
        Cf[(size_t)row * N + col] = acc[mt][nt][r] + bias[col];
      }
    }
  }
}

// ---------------- flash attention, LDS-shared KV, 64-row blocks, MFMA32 PV (R9, proven) ----------------
__global__ __launch_bounds__(256, 4) void attn_kernel(
    const uint16_t* __restrict__ Qh, const uint16_t* __restrict__ Kh,
    const uint16_t* __restrict__ Vh, uint16_t* __restrict__ out) {
  __shared__ __align__(16) uint16_t Ks[2][4096];
  __shared__ __align__(16) uint16_t Vs[2][4096];
  const int tid = threadIdx.x;
  const int wave = tid >> 6;
  const int lane = tid & 63;
  const int quad = lane >> 4;
  const int l16 = lane & 15;
  const int bx = blockIdx.x;
  // bx = g*8 + xcd ; g = it + 32*hhi + 64*ib ; h = hhi*8 + xcd
  const int xcd = bx & 7;
  const int g = bx >> 3;
  const int it = g & 31;            // 32 i-tiles of 64 rows
  const int h = ((g >> 5) & 1) * 8 + xcd;
  const int ib = g >> 6;
  const int i0 = it * 64 + wave * 16;
  const size_t hb = (size_t)(ib * 16 + h) * 131072;

  // Q fragments (B-operand of S^T MFMA): lane l16 = q-row, k = quad*8+e
  short8 qf[2];
#pragma unroll
  for (int kc = 0; kc < 2; ++kc)
    qf[kc] = *(const short8*)(Qh + hb + (size_t)(i0 + l16) * 64 + kc * 32 + quad * 8);

  f32x4 o[4], o4;
  o4 = (f32x4){0.f, 0.f, 0.f, 0.f};
#pragma unroll
  for (int t = 0; t < 4; ++t) o[t] = (f32x4){0.f, 0.f, 0.f, 0.f};

  const short8 ones8 = {(short)0x3F80, (short)0x3F80, (short)0x3F80, (short)0x3F80,
                        (short)0x3F80, (short)0x3F80, (short)0x3F80, (short)0x3F80};

  // staging: this wave stages elems [wave*1024, wave*1024+1024) of each tile
  const uint16_t* gK = Kh + hb + wave * 1024 + lane * 8;
  const uint16_t* gV = Vh + hb + wave * 1024 + lane * 8;
  const int so = wave * 1024;

  // prologue: stage tile 0 into buf 0
  load_lds16(gK, &Ks[0][so]);
  load_lds16(gK + 512, &Ks[0][so + 512]);
  load_lds16(gV, &Vs[0][so]);
  load_lds16(gV + 512, &Vs[0][so + 512]);
  __syncthreads();

#pragma unroll 2
  for (int t = 0; t < 32; ++t) {
    const int cur = t & 1;
    // stage tile t+1 into the other buffer (hidden under this tile's compute)
    if (t < 31) {
      const size_t goff = (size_t)(t + 1) * 4096;
      load_lds16(gK + goff, &Ks[cur ^ 1][so]);
      load_lds16(gK + goff + 512, &Ks[cur ^ 1][so + 512]);
      load_lds16(gV + goff, &Vs[cur ^ 1][so]);
      load_lds16(gV + goff + 512, &Vs[cur ^ 1][so + 512]);
    }

    // K frags from LDS (same frag order as the global layout)
    short8 kf[8];
#pragma unroll
    for (int i = 0; i < 8; ++i) kf[i] = *(const short8*)&Ks[cur][i * 512 + lane * 8];

    // S^T = K . Q^T : lane holds q-row l16, j = st*16 + quad*4 + r
    f32x4 s[4];
#pragma unroll
    for (int st = 0; st < 4; ++st) {
      f32x4 sc = (f32x4){0.f, 0.f, 0.f, 0.f};
      sc = MFMA32(kf[st * 2 + 0], qf[0], sc);
      sc = MFMA32(kf[st * 2 + 1], qf[1], sc);
      s[st] = sc;
    }

    // V frags (sigma-permuted B-frags; i = st2*4 + dt)
    short8 v8[8];
#pragma unroll
    for (int i = 0; i < 8; ++i) v8[i] = *(const short8*)&Vs[cur][i * 512 + lane * 8];

    // P = exp2(s), packed straight into sigma-ordered x32 A-frags:
    // p8[st2][e] with e = h*4 + r <-> j = st2*32 + h*16 + quad*4 + r
    short8 p8[2];
#pragma unroll
    for (int st2 = 0; st2 < 2; ++st2) {
      short8 p;
#pragma unroll
      for (int hh = 0; hh < 2; ++hh)
#pragma unroll
        for (int r = 0; r < 4; ++r)
          p[hh * 4 + r] =
              (short)f32_to_bf16_fast(__builtin_amdgcn_exp2f(s[st2 * 2 + hh][r]));
      p8[st2] = p;
    }

    // O += P V via MFMA32 (8 PV + 2 row-sum per tile)
#pragma unroll
    for (int st2 = 0; st2 < 2; ++st2) {
      o4 = MFMA32(p8[st2], ones8, o4);
#pragma unroll
      for (int dt = 0; dt < 4; ++dt)
        o[dt] = MFMA32(p8[st2], v8[st2 * 4 + dt], o[dt]);
    }

    __syncthreads();
  }

  // epilogue: O /= l, store bf16 [B*2048][1024]
#pragma unroll
  for (int r = 0; r < 4; ++r) {
    const float inv = 1.0f / o4[r];
    const int row = i0 + quad * 4 + r;
    const size_t obase = (size_t)(ib * 2048 + row) * 1024 + h * 64;
#pragma unroll
    for (int tt = 0; tt < 4; ++tt)
      out[obase + tt * 16 + l16] = f32_to_bf16(o[tt][r] * inv);
  }
}

// ---------------- launch ----------------
extern "C" void kernel_launch(void* const* d_in, const int* in_sizes, int n_in,
                              void* d_out, int out_size, void* d_ws, size_t ws_size,
                              hipStream_t stream) {
  const float* x = (const float*)d_in[0];     // [2,2048,1024]
  const float* Wqkv = (const float*)d_in[1];  // [3072,1024]
  const float* Wout = (const float*)d_in[2];  // [1024,1024]
  const float* bout = (const float*)d_in[3];  // [1024]

  uint16_t* xb = (uint16_t*)d_ws;                       // 4096*1024
  uint16_t* wqkvb = xb + (size_t)4096 * 1024;           // 3072*1024
  uint16_t* woutb = wqkvb + (size_t)3072 * 1024;        // 1024*1024
  uint16_t* qh = woutb + (size_t)1024 * 1024;           // 32 heads * 131072
  uint16_t* kh = qh + (size_t)32 * 131072;
  uint16_t* vh = kh + (size_t)32 * 131072;
  uint16_t* attnb = vh + (size_t)32 * 131072;           // 4096*1024

  cvt3_kernel<<<8192, 256, 0, stream>>>(x, Wqkv, Wout, xb, wqkvb, woutb);

  gemm_qkv_kernel<<<dim3(4096 / 128, 3072 / 64), 256, 0, stream>>>(
      xb, wqkvb, qh, kh, vh);

  attn_kernel<<<1024, 256, 0, stream>>>(qh, kh, vh, attnb);

  gemm_out_kernel<<<dim3(4096 / 128, 1024 / 64), 256, 0, stream>>>(
      attnb, woutb, (float*)d_out, bout);
}

// Round 12
// 178.396 us; speedup vs baseline: 1.0541x; 1.0117x over previous
//
#include <hip/hip_runtime.h>
#include <stdint.h>

typedef __attribute__((ext_vector_type(8))) short short8;
typedef __attribute__((ext_vector_type(4))) short bf16x4;
typedef __attribute__((ext_vector_type(4))) float f32x4;

#define MFMA32(a, b, c) __builtin_amdgcn_mfma_f32_16x16x32_bf16((a), (b), (c), 0, 0, 0)

__device__ __forceinline__ uint16_t f32_to_bf16(float f) {
  union { float f; uint32_t u; } v; v.f = f;
  uint32_t u = v.u;
  u += 0x7FFFu + ((u >> 16) & 1u);   // RTNE
  return (uint16_t)(u >> 16);
}
__device__ __forceinline__ uint16_t f32_to_bf16_fast(float f) {
  union { float f; uint32_t u; } v; v.f = f;
  return (uint16_t)((v.u + 0x8000u) >> 16);   // round-half-up (P only)
}

__device__ __forceinline__ void load_lds16(const uint16_t* g, uint16_t* l) {
  __builtin_amdgcn_global_load_lds(
      (const __attribute__((address_space(1))) uint32_t*)g,
      (__attribute__((address_space(3))) uint32_t*)l, 16, 0, 0);
}

// ---------------- fused f32 -> bf16 conversion (x, Wqkv, Wout) ----------------
__global__ __launch_bounds__(256) void cvt3_kernel(
    const float* __restrict__ x, const float* __restrict__ w1,
    const float* __restrict__ w2, uint16_t* __restrict__ xb,
    uint16_t* __restrict__ w1b, uint16_t* __restrict__ w2b) {
  const int i = blockIdx.x * 256 + threadIdx.x;  // 2,097,152 float4 total
  const float4* src;
  ushort4* dst;
  int off;
  if (i < 1048576) { src = (const float4*)x;  dst = (ushort4*)xb;  off = i; }
  else if (i < 1835008) { src = (const float4*)w1; dst = (ushort4*)w1b; off = i - 1048576; }
  else { src = (const float4*)w2; dst = (ushort4*)w2b; off = i - 1835008; }
  const float4 v = src[off];
  ushort4 o;
  o.x = f32_to_bf16(v.x);
  o.y = f32_to_bf16(v.y);
  o.z = f32_to_bf16(v.z);
  o.w = f32_to_bf16(v.w);
  dst[off] = o;
}

// ---------------- QKV GEMM: 128x64 tile, BK=64, single-buffer serial (R11, proven) ----------------
__global__ __launch_bounds__(256) void gemm_qkv_kernel(
    const uint16_t* __restrict__ A, const uint16_t* __restrict__ Bt,
    uint16_t* __restrict__ Qh, uint16_t* __restrict__ Kh, uint16_t* __restrict__ Vh) {
  __shared__ __align__(16) uint16_t As[128 * 64];   // 16 KB
  __shared__ __align__(16) uint16_t Bs[64 * 64];    // 8 KB
  const int tid = threadIdx.x;
  const int wave = tid >> 6;
  const int lane = tid & 63;
  const int quad = lane >> 4;
  const int l16 = lane & 15;
  const int row0 = blockIdx.x * 128;
  const int col0 = blockIdx.y * 64;
  const int wm = (wave >> 1) * 64;
  const int wn = (wave & 1) * 32;
  const int K = 1024;

  f32x4 acc[4][2];
#pragma unroll
  for (int a = 0; a < 4; ++a)
#pragma unroll
    for (int b = 0; b < 2; ++b) acc[a][b] = (f32x4){0.f, 0.f, 0.f, 0.f};

  // staging: source chunk pre-swizzled (T2 write side); read swizzle cancels it.
  const int swz8 = ((lane & 7) ^ ((lane >> 3) & 7)) * 8;
  const uint16_t* gA = A + (size_t)(row0 + wave * 32 + (lane >> 3)) * K + swz8;
  const uint16_t* gB = Bt + (size_t)(col0 + wave * 16 + (lane >> 3)) * K + swz8;

  for (int k0 = 0; k0 < K; k0 += 64) {
#pragma unroll
    for (int s = 0; s < 4; ++s)
      load_lds16(gA + (size_t)s * 8 * K + k0, &As[(wave * 32 + s * 8) * 64]);
#pragma unroll
    for (int s = 0; s < 2; ++s)
      load_lds16(gB + (size_t)s * 8 * K + k0, &Bs[(wave * 16 + s * 8) * 64]);
    __syncthreads();
#pragma unroll
    for (int ks = 0; ks < 2; ++ks) {
      const int cswz = (((ks * 4 + quad) ^ (l16 & 7)) * 8);
      short8 af[4], bf[2];
#pragma unroll
      for (int mt = 0; mt < 4; ++mt)
        af[mt] = *(const short8*)&As[(wm + mt * 16 + l16) * 64 + cswz];
#pragma unroll
      for (int nt = 0; nt < 2; ++nt)
        bf[nt] = *(const short8*)&Bs[(wn + nt * 16 + l16) * 64 + cswz];
#pragma unroll
      for (int mt = 0; mt < 4; ++mt)
#pragma unroll
        for (int nt = 0; nt < 2; ++nt)
          acc[mt][nt] = MFMA32(af[mt], bf[nt], acc[mt][nt]);
    }
    __syncthreads();
  }

  // epilogue: qkv swizzle (verbatim R9 formulas)
#pragma unroll
  for (int mt = 0; mt < 4; ++mt) {
#pragma unroll
    for (int nt = 0; nt < 2; ++nt) {
      const int col = col0 + wn + nt * 16 + l16;
      const int which = col >> 10;          // 0=q 1=k 2=v (block-uniform, 1024%64==0)
      const int hc = (col & 1023) >> 6;
      const int d = col & 63;
#pragma unroll
      for (int r = 0; r < 4; ++r) {
        const int row = row0 + wm + mt * 16 + quad * 4 + r;
        const float val = acc[mt][nt][r];
        const int b = row >> 11;
        const int nn = row & 2047;
        const size_t hb = (size_t)(b * 16 + hc) * 131072;
        if (which == 0) {
          // fold softmax scale (1/8) and log2(e) into Q
          Qh[hb + (size_t)nn * 64 + d] = f32_to_bf16(val * 0.1803368801111244f);
        } else if (which == 1) {
          const uint16_t bv = f32_to_bf16(val);
          // K: 16x16x32 A-frag order [jt][st][kc][lane=qd*16+j16][e8]
          const int jt = nn >> 6, st = (nn >> 4) & 3, j16 = nn & 15;
          const int kc = d >> 5, qd = (d >> 3) & 3, e = d & 7;
          Kh[hb + jt * 4096 + st * 1024 + kc * 512 + (qd * 16 + j16) * 8 + e] = bv;
        } else {
          const uint16_t bv = f32_to_bf16(val);
          // V: 16x16x32 B-frag, sigma-permuted j (R9):
          const int jt = nn >> 6, jp = nn & 63;
          const int st2 = jp >> 5, j32 = jp & 31;
          const int qv = (j32 >> 2) & 3, e = (j32 >> 4) * 4 + (j32 & 3);
          const int dt = d >> 4, d16 = d & 15;
          Vh[hb + jt * 4096 + (st2 * 4 + dt) * 512 + (qv * 16 + d16) * 8 + e] = bv;
        }
      }
    }
  }
}

// ---------------- output-proj GEMM: 64x64 tile, BK=64, single-buffer serial ----------------
// R12: the 128x64 gemm_out grid was 512 blocks = 2 blocks/CU on the serial
// stage->drain->compute shape -- the same latency-bound regime that capped
// gemm_qkv at 3 blocks/CU (R9: MfmaUtil 18.6). Proven lever (R7, R11): shrink
// tile for more co-resident blocks. 64x64: grid 64x16 = 1024 = 4 blocks/CU
// (LDS 16 KB, acc 16 VGPR, per-wave 32x32). Swizzle algebra unchanged (all row
// offsets stay multiples of 8 -> row&7 == l16&7).
__global__ __launch_bounds__(256) void gemm_out_kernel(
    const uint16_t* __restrict__ A, const uint16_t* __restrict__ Bt,
    float* __restrict__ Cf, const float* __restrict__ bias) {
  __shared__ __align__(16) uint16_t As[64 * 64];    // 8 KB
  __shared__ __align__(16) uint16_t Bs[64 * 64];    // 8 KB
  const int tid = threadIdx.x;
  const int wave = tid >> 6;
  const int lane = tid & 63;
  const int quad = lane >> 4;
  const int l16 = lane & 15;
  const int row0 = blockIdx.x * 64;
  const int col0 = blockIdx.y * 64;
  const int wm = (wave >> 1) * 32;
  const int wn = (wave & 1) * 32;
  const int K = 1024;
  const int N = 1024;

  f32x4 acc[2][2];
#pragma unroll
  for (int a = 0; a < 2; ++a)
#pragma unroll
    for (int b = 0; b < 2; ++b) acc[a][b] = (f32x4){0.f, 0.f, 0.f, 0.f};

  const int swz8 = ((lane & 7) ^ ((lane >> 3) & 7)) * 8;
  const uint16_t* gA = A + (size_t)(row0 + wave * 16 + (lane >> 3)) * K + swz8;
  const uint16_t* gB = Bt + (size_t)(col0 + wave * 16 + (lane >> 3)) * K + swz8;

  for (int k0 = 0; k0 < K; k0 += 64) {
#pragma unroll
    for (int s = 0; s < 2; ++s) {
      load_lds16(gA + (size_t)s * 8 * K + k0, &As[(wave * 16 + s * 8) * 64]);
      load_lds16(gB + (size_t)s * 8 * K + k0, &Bs[(wave * 16 + s * 8) * 64]);
    }
    __syncthreads();
#pragma unroll
    for (int ks = 0; ks < 2; ++ks) {
      const int cswz = (((ks * 4 + quad) ^ (l16 & 7)) * 8);
      short8 af[2], bf[2];
#pragma unroll
      for (int mt = 0; mt < 2; ++mt)
        af[mt] = *(const short8*)&As[(wm + mt * 16 + l16) * 64 + cswz];
#pragma unroll
      for (int nt = 0; nt < 2; ++nt)
        bf[nt] = *(const short8*)&Bs[(wn + nt * 16 + l16) * 64 + cswz];
#pragma unroll
      for (int mt = 0; mt < 2; ++mt)
#pragma unroll
        for (int nt = 0; nt < 2; ++nt)
          acc[mt][nt] = MFMA32(af[mt], bf[nt], acc[mt][nt]);
    }
    __syncthreads();
  }

#pragma unroll
  for (int mt = 0; mt < 2; ++mt) {
#pragma unroll
    for (int nt = 0; nt < 2; ++nt) {
      const int col = col0 + wn + nt * 16 + l16;
#pragma unroll
      for (int r = 0; r < 4; ++r) {
        const int row = row0 + wm + mt * 16 + quad * 4 + r;
        Cf[(size_t)row * N + col] = acc[mt][nt][r] + bias[col];
      }
    }
  }
}

// ---------------- flash attention, LDS-shared KV, 64-row blocks, MFMA32 PV ----------------
// R12: + s_setprio(1) around the QK and PV MFMA clusters (T5). Mechanism: waves
// drift within a tile (exp2/VALU vs MFMA phases) and 4 independent blocks/CU
// coexist -> scheduler can favor the MFMA-entering wave. (m191: attn +4-7%;
// m190: null on lockstep GEMM -- if this is null here, structure is
// co-issue-balanced and we revert.)
__global__ __launch_bounds__(256, 4) void attn_kernel(
    const uint16_t* __restrict__ Qh, const uint16_t* __restrict__ Kh,
    const uint16_t* __restrict__ Vh, uint16_t* __restrict__ out) {
  __shared__ __align__(16) uint16_t Ks[2][4096];
  __shared__ __align__(16) uint16_t Vs[2][4096];
  const int tid = threadIdx.x;
  const int wave = tid >> 6;
  const int lane = tid & 63;
  const int quad = lane >> 4;
  const int l16 = lane & 15;
  const int bx = blockIdx.x;
  // bx = g*8 + xcd ; g = it + 32*hhi + 64*ib ; h = hhi*8 + xcd
  const int xcd = bx & 7;
  const int g = bx >> 3;
  const int it = g & 31;            // 32 i-tiles of 64 rows
  const int h = ((g >> 5) & 1) * 8 + xcd;
  const int ib = g >> 6;
  const int i0 = it * 64 + wave * 16;
  const size_t hb = (size_t)(ib * 16 + h) * 131072;

  // Q fragments (B-operand of S^T MFMA): lane l16 = q-row, k = quad*8+e
  short8 qf[2];
#pragma unroll
  for (int kc = 0; kc < 2; ++kc)
    qf[kc] = *(const short8*)(Qh + hb + (size_t)(i0 + l16) * 64 + kc * 32 + quad * 8);

  f32x4 o[4], o4;
  o4 = (f32x4){0.f, 0.f, 0.f, 0.f};
#pragma unroll
  for (int t = 0; t < 4; ++t) o[t] = (f32x4){0.f, 0.f, 0.f, 0.f};

  const short8 ones8 = {(short)0x3F80, (short)0x3F80, (short)0x3F80, (short)0x3F80,
                        (short)0x3F80, (short)0x3F80, (short)0x3F80, (short)0x3F80};

  // staging: this wave stages elems [wave*1024, wave*1024+1024) of each tile
  const uint16_t* gK = Kh + hb + wave * 1024 + lane * 8;
  const uint16_t* gV = Vh + hb + wave * 1024 + lane * 8;
  const int so = wave * 1024;

  // prologue: stage tile 0 into buf 0
  load_lds16(gK, &Ks[0][so]);
  load_lds16(gK + 512, &Ks[0][so + 512]);
  load_lds16(gV, &Vs[0][so]);
  load_lds16(gV + 512, &Vs[0][so + 512]);
  __syncthreads();

#pragma unroll 2
  for (int t = 0; t < 32; ++t) {
    const int cur = t & 1;
    // stage tile t+1 into the other buffer (hidden under this tile's compute)
    if (t < 31) {
      const size_t goff = (size_t)(t + 1) * 4096;
      load_lds16(gK + goff, &Ks[cur ^ 1][so]);
      load_lds16(gK + goff + 512, &Ks[cur ^ 1][so + 512]);
      load_lds16(gV + goff, &Vs[cur ^ 1][so]);
      load_lds16(gV + goff + 512, &Vs[cur ^ 1][so + 512]);
    }

    // K frags from LDS (same frag order as the global layout)
    short8 kf[8];
#pragma unroll
    for (int i = 0; i < 8; ++i) kf[i] = *(const short8*)&Ks[cur][i * 512 + lane * 8];

    // S^T = K . Q^T : lane holds q-row l16, j = st*16 + quad*4 + r
    f32x4 s[4];
    __builtin_amdgcn_s_setprio(1);
#pragma unroll
    for (int st = 0; st < 4; ++st) {
      f32x4 sc = (f32x4){0.f, 0.f, 0.f, 0.f};
      sc = MFMA32(kf[st * 2 + 0], qf[0], sc);
      sc = MFMA32(kf[st * 2 + 1], qf[1], sc);
      s[st] = sc;
    }
    __builtin_amdgcn_s_setprio(0);

    // V frags (sigma-permuted B-frags; i = st2*4 + dt)
    short8 v8[8];
#pragma unroll
    for (int i = 0; i < 8; ++i) v8[i] = *(const short8*)&Vs[cur][i * 512 + lane * 8];

    // P = exp2(s), packed straight into sigma-ordered x32 A-frags:
    // p8[st2][e] with e = h*4 + r <-> j = st2*32 + h*16 + quad*4 + r
    short8 p8[2];
#pragma unroll
    for (int st2 = 0; st2 < 2; ++st2) {
      short8 p;
#pragma unroll
      for (int hh = 0; hh < 2; ++hh)
#pragma unroll
        for (int r = 0; r < 4; ++r)
          p[hh * 4 + r] =
              (short)f32_to_bf16_fast(__builtin_amdgcn_exp2f(s[st2 * 2 + hh][r]));
      p8[st2] = p;
    }

    // O += P V via MFMA32 (8 PV + 2 row-sum per tile)
    __builtin_amdgcn_s_setprio(1);
#pragma unroll
    for (int st2 = 0; st2 < 2; ++st2) {
      o4 = MFMA32(p8[st2], ones8, o4);
#pragma unroll
      for (int dt = 0; dt < 4; ++dt)
        o[dt] = MFMA32(p8[st2], v8[st2 * 4 + dt], o[dt]);
    }
    __builtin_amdgcn_s_setprio(0);

    __syncthreads();
  }

  // epilogue: O /= l, store bf16 [B*2048][1024]
#pragma unroll
  for (int r = 0; r < 4; ++r) {
    const float inv = 1.0f / o4[r];
    const int row = i0 + quad * 4 + r;
    const size_t obase = (size_t)(ib * 2048 + row) * 1024 + h * 64;
#pragma unroll
    for (int tt = 0; tt < 4; ++tt)
      out[obase + tt * 16 + l16] = f32_to_bf16(o[tt][r] * inv);
  }
}

// ---------------- launch ----------------
extern "C" void kernel_launch(void* const* d_in, const int* in_sizes, int n_in,
                              void* d_out, int out_size, void* d_ws, size_t ws_size,
                              hipStream_t stream) {
  const float* x = (const float*)d_in[0];     // [2,2048,1024]
  const float* Wqkv = (const float*)d_in[1];  // [3072,1024]
  const float* Wout = (const float*)d_in[2];  // [1024,1024]
  const float* bout = (const float*)d_in[3];  // [1024]

  uint16_t* xb = (uint16_t*)d_ws;                       // 4096*1024
  uint16_t* wqkvb = xb + (size_t)4096 * 1024;           // 3072*1024
  uint16_t* woutb = wqkvb + (size_t)3072 * 1024;        // 1024*1024
  uint16_t* qh = woutb + (size_t)1024 * 1024;           // 32 heads * 131072
  uint16_t* kh = qh + (size_t)32 * 131072;
  uint16_t* vh = kh + (size_t)32 * 131072;
  uint16_t* attnb = vh + (size_t)32 * 131072;           // 4096*1024

  cvt3_kernel<<<8192, 256, 0, stream>>>(x, Wqkv, Wout, xb, wqkvb, woutb);

  gemm_qkv_kernel<<<dim3(4096 / 128, 3072 / 64), 256, 0, stream>>>(
      xb, wqkvb, qh, kh, vh);

  attn_kernel<<<1024, 256, 0, stream>>>(qh, kh, vh, attnb);

  gemm_out_kernel<<<dim3(4096 / 64, 1024 / 64), 256, 0, stream>>>(
      attnb, woutb, (float*)d_out, bout);
}

// Round 13
// 177.065 us; speedup vs baseline: 1.0620x; 1.0075x over previous
//
#include <hip/hip_runtime.h>
#include <stdint.h>

typedef __attribute__((ext_vector_type(8))) short short8;
typedef __attribute__((ext_vector_type(4))) short bf16x4;
typedef __attribute__((ext_vector_type(4))) float f32x4;

#define MFMA32(a, b, c) __builtin_amdgcn_mfma_f32_16x16x32_bf16((a), (b), (c), 0, 0, 0)

__device__ __forceinline__ uint16_t f32_to_bf16(float f) {
  union { float f; uint32_t u; } v; v.f = f;
  uint32_t u = v.u;
  u += 0x7FFFu + ((u >> 16) & 1u);   // RTNE
  return (uint16_t)(u >> 16);
}
__device__ __forceinline__ uint16_t f32_to_bf16_fast(float f) {
  union { float f; uint32_t u; } v; v.f = f;
  return (uint16_t)((v.u + 0x8000u) >> 16);   // round-half-up (P only)
}

__device__ __forceinline__ void load_lds16(const uint16_t* g, uint16_t* l) {
  __builtin_amdgcn_global_load_lds(
      (const __attribute__((address_space(1))) uint32_t*)g,
      (__attribute__((address_space(3))) uint32_t*)l, 16, 0, 0);
}

// ---------------- fused f32 -> bf16 conversion (x, Wqkv, Wout) ----------------
__global__ __launch_bounds__(256) void cvt3_kernel(
    const float* __restrict__ x, const float* __restrict__ w1,
    const float* __restrict__ w2, uint16_t* __restrict__ xb,
    uint16_t* __restrict__ w1b, uint16_t* __restrict__ w2b) {
  const int i = blockIdx.x * 256 + threadIdx.x;  // 2,097,152 float4 total
  const float4* src;
  ushort4* dst;
  int off;
  if (i < 1048576) { src = (const float4*)x;  dst = (ushort4*)xb;  off = i; }
  else if (i < 1835008) { src = (const float4*)w1; dst = (ushort4*)w1b; off = i - 1048576; }
  else { src = (const float4*)w2; dst = (ushort4*)w2b; off = i - 1835008; }
  const float4 v = src[off];
  ushort4 o;
  o.x = f32_to_bf16(v.x);
  o.y = f32_to_bf16(v.y);
  o.z = f32_to_bf16(v.z);
  o.w = f32_to_bf16(v.w);
  dst[off] = o;
}

// ---------------- QKV GEMM: 128x64 tile, BK=64, single-buffer serial (R11, proven) ----------------
__global__ __launch_bounds__(256) void gemm_qkv_kernel(
    const uint16_t* __restrict__ A, const uint16_t* __restrict__ Bt,
    uint16_t* __restrict__ Qh, uint16_t* __restrict__ Kh, uint16_t* __restrict__ Vh) {
  __shared__ __align__(16) uint16_t As[128 * 64];   // 16 KB
  __shared__ __align__(16) uint16_t Bs[64 * 64];    // 8 KB
  const int tid = threadIdx.x;
  const int wave = tid >> 6;
  const int lane = tid & 63;
  const int quad = lane >> 4;
  const int l16 = lane & 15;
  const int row0 = blockIdx.x * 128;
  const int col0 = blockIdx.y * 64;
  const int wm = (wave >> 1) * 64;
  const int wn = (wave & 1) * 32;
  const int K = 1024;

  f32x4 acc[4][2];
#pragma unroll
  for (int a = 0; a < 4; ++a)
#pragma unroll
    for (int b = 0; b < 2; ++b) acc[a][b] = (f32x4){0.f, 0.f, 0.f, 0.f};

  // staging: source chunk pre-swizzled (T2 write side); read swizzle cancels it.
  const int swz8 = ((lane & 7) ^ ((lane >> 3) & 7)) * 8;
  const uint16_t* gA = A + (size_t)(row0 + wave * 32 + (lane >> 3)) * K + swz8;
  const uint16_t* gB = Bt + (size_t)(col0 + wave * 16 + (lane >> 3)) * K + swz8;

  for (int k0 = 0; k0 < K; k0 += 64) {
#pragma unroll
    for (int s = 0; s < 4; ++s)
      load_lds16(gA + (size_t)s * 8 * K + k0, &As[(wave * 32 + s * 8) * 64]);
#pragma unroll
    for (int s = 0; s < 2; ++s)
      load_lds16(gB + (size_t)s * 8 * K + k0, &Bs[(wave * 16 + s * 8) * 64]);
    __syncthreads();
#pragma unroll
    for (int ks = 0; ks < 2; ++ks) {
      const int cswz = (((ks * 4 + quad) ^ (l16 & 7)) * 8);
      short8 af[4], bf[2];
#pragma unroll
      for (int mt = 0; mt < 4; ++mt)
        af[mt] = *(const short8*)&As[(wm + mt * 16 + l16) * 64 + cswz];
#pragma unroll
      for (int nt = 0; nt < 2; ++nt)
        bf[nt] = *(const short8*)&Bs[(wn + nt * 16 + l16) * 64 + cswz];
#pragma unroll
      for (int mt = 0; mt < 4; ++mt)
#pragma unroll
        for (int nt = 0; nt < 2; ++nt)
          acc[mt][nt] = MFMA32(af[mt], bf[nt], acc[mt][nt]);
    }
    __syncthreads();
  }

  // epilogue: qkv swizzle (verbatim R9 formulas)
#pragma unroll
  for (int mt = 0; mt < 4; ++mt) {
#pragma unroll
    for (int nt = 0; nt < 2; ++nt) {
      const int col = col0 + wn + nt * 16 + l16;
      const int which = col >> 10;          // 0=q 1=k 2=v (block-uniform, 1024%64==0)
      const int hc = (col & 1023) >> 6;
      const int d = col & 63;
#pragma unroll
      for (int r = 0; r < 4; ++r) {
        const int row = row0 + wm + mt * 16 + quad * 4 + r;
        const float val = acc[mt][nt][r];
        const int b = row >> 11;
        const int nn = row & 2047;
        const size_t hb = (size_t)(b * 16 + hc) * 131072;
        if (which == 0) {
          // fold softmax scale (1/8) and log2(e) into Q
          Qh[hb + (size_t)nn * 64 + d] = f32_to_bf16(val * 0.1803368801111244f);
        } else if (which == 1) {
          const uint16_t bv = f32_to_bf16(val);
          // K: 16x16x32 A-frag order [jt][st][kc][lane=qd*16+j16][e8]
          const int jt = nn >> 6, st = (nn >> 4) & 3, j16 = nn & 15;
          const int kc = d >> 5, qd = (d >> 3) & 3, e = d & 7;
          Kh[hb + jt * 4096 + st * 1024 + kc * 512 + (qd * 16 + j16) * 8 + e] = bv;
        } else {
          const uint16_t bv = f32_to_bf16(val);
          // V: 16x16x32 B-frag, sigma-permuted j (R9):
          const int jt = nn >> 6, jp = nn & 63;
          const int st2 = jp >> 5, j32 = jp & 31;
          const int qv = (j32 >> 2) & 3, e = (j32 >> 4) * 4 + (j32 & 3);
          const int dt = d >> 4, d16 = d & 15;
          Vh[hb + jt * 4096 + (st2 * 4 + dt) * 512 + (qv * 16 + d16) * 8 + e] = bv;
        }
      }
    }
  }
}

// ---------------- output-proj GEMM: 64x64 tile, BK=64, single-buffer serial (R12) ----------------
__global__ __launch_bounds__(256) void gemm_out_kernel(
    const uint16_t* __restrict__ A, const uint16_t* __restrict__ Bt,
    float* __restrict__ Cf, const float* __restrict__ bias) {
  __shared__ __align__(16) uint16_t As[64 * 64];    // 8 KB
  __shared__ __align__(16) uint16_t Bs[64 * 64];    // 8 KB
  const int tid = threadIdx.x;
  const int wave = tid >> 6;
  const int lane = tid & 63;
  const int quad = lane >> 4;
  const int l16 = lane & 15;
  const int row0 = blockIdx.x * 64;
  const int col0 = blockIdx.y * 64;
  const int wm = (wave >> 1) * 32;
  const int wn = (wave & 1) * 32;
  const int K = 1024;
  const int N = 1024;

  f32x4 acc[2][2];
#pragma unroll
  for (int a = 0; a < 2; ++a)
#pragma unroll
    for (int b = 0; b < 2; ++b) acc[a][b] = (f32x4){0.f, 0.f, 0.f, 0.f};

  const int swz8 = ((lane & 7) ^ ((lane >> 3) & 7)) * 8;
  const uint16_t* gA = A + (size_t)(row0 + wave * 16 + (lane >> 3)) * K + swz8;
  const uint16_t* gB = Bt + (size_t)(col0 + wave * 16 + (lane >> 3)) * K + swz8;

  for (int k0 = 0; k0 < K; k0 += 64) {
#pragma unroll
    for (int s = 0; s < 2; ++s) {
      load_lds16(gA + (size_t)s * 8 * K + k0, &As[(wave * 16 + s * 8) * 64]);
      load_lds16(gB + (size_t)s * 8 * K + k0, &Bs[(wave * 16 + s * 8) * 64]);
    }
    __syncthreads();
#pragma unroll
    for (int ks = 0; ks < 2; ++ks) {
      const int cswz = (((ks * 4 + quad) ^ (l16 & 7)) * 8);
      short8 af[2], bf[2];
#pragma unroll
      for (int mt = 0; mt < 2; ++mt)
        af[mt] = *(const short8*)&As[(wm + mt * 16 + l16) * 64 + cswz];
#pragma unroll
      for (int nt = 0; nt < 2; ++nt)
        bf[nt] = *(const short8*)&Bs[(wn + nt * 16 + l16) * 64 + cswz];
#pragma unroll
      for (int mt = 0; mt < 2; ++mt)
#pragma unroll
        for (int nt = 0; nt < 2; ++nt)
          acc[mt][nt] = MFMA32(af[mt], bf[nt], acc[mt][nt]);
    }
    __syncthreads();
  }

#pragma unroll
  for (int mt = 0; mt < 2; ++mt) {
#pragma unroll
    for (int nt = 0; nt < 2; ++nt) {
      const int col = col0 + wn + nt * 16 + l16;
#pragma unroll
      for (int r = 0; r < 4; ++r) {
        const int row = row0 + wm + mt * 16 + quad * 4 + r;
        Cf[(size_t)row * N + col] = acc[mt][nt][r] + bias[col];
      }
    }
  }
}

// ---------------- flash attention: 2q x 2k wave-split, LDS reads halved ----------------
// R12 counters: MfmaUtil 34 / VALUBusy 43, but per-pipe arithmetic puts the
// LDS port highest (~27us of the 45): all 4 waves re-read the SAME 8 K-frags +
// 8 V-frags per tile (q-split only -> 4x duplication). R13: waves split 2x2
// over (q,k): wave (qg,kg) = 32 q-rows x kg-half (32 keys). Per wave per tile:
// 4 K + 4 V ds_reads (HALVED), MFMA/exp2 totals unchanged. The no-max linear
// softmax makes k-splitting exact: O = O_k0 + O_k1, l = l0 + l1 -- combined
// once at the end through the (dead) K/V LDS buffers (R2 precedent, passed).
// sigma-layout: each wave's P slice is exactly one x32 A-frag (st2 == kg);
// V slice = frags (kg*4+dt). Same addresses, per-wave subset.
__global__ __launch_bounds__(256, 4) void attn_kernel(
    const uint16_t* __restrict__ Qh, const uint16_t* __restrict__ Kh,
    const uint16_t* __restrict__ Vh, uint16_t* __restrict__ out) {
  __shared__ __align__(16) uint16_t Ks[2][4096];
  __shared__ __align__(16) uint16_t Vs[2][4096];
  const int tid = threadIdx.x;
  const int wave = tid >> 6;
  const int lane = tid & 63;
  const int quad = lane >> 4;
  const int l16 = lane & 15;
  const int qg = wave >> 1;         // q-group: 32 rows
  const int kg = wave & 1;          // k-group: 32 keys of each 64-key tile
  const int bx = blockIdx.x;
  // bx = g*8 + xcd ; g = it + 32*hhi + 64*ib ; h = hhi*8 + xcd
  const int xcd = bx & 7;
  const int g = bx >> 3;
  const int it = g & 31;            // 32 i-tiles of 64 rows
  const int h = ((g >> 5) & 1) * 8 + xcd;
  const int ib = g >> 6;
  const int i0 = it * 64 + qg * 32;
  const size_t hb = (size_t)(ib * 16 + h) * 131072;

  // Q fragments for 32 rows (B-operand of S^T MFMA): lane l16 = q-row
  short8 qf[2][2];
#pragma unroll
  for (int m = 0; m < 2; ++m)
#pragma unroll
    for (int kc = 0; kc < 2; ++kc)
      qf[m][kc] = *(const short8*)(Qh + hb + (size_t)(i0 + m * 16 + l16) * 64 +
                                   kc * 32 + quad * 8);

  f32x4 o[2][4], o4[2];
#pragma unroll
  for (int m = 0; m < 2; ++m) {
    o4[m] = (f32x4){0.f, 0.f, 0.f, 0.f};
#pragma unroll
    for (int t = 0; t < 4; ++t) o[m][t] = (f32x4){0.f, 0.f, 0.f, 0.f};
  }

  const short8 ones8 = {(short)0x3F80, (short)0x3F80, (short)0x3F80, (short)0x3F80,
                        (short)0x3F80, (short)0x3F80, (short)0x3F80, (short)0x3F80};

  // staging: this wave stages elems [wave*1024, wave*1024+1024) of each tile
  const uint16_t* gK = Kh + hb + wave * 1024 + lane * 8;
  const uint16_t* gV = Vh + hb + wave * 1024 + lane * 8;
  const int so = wave * 1024;

  // prologue: stage tile 0 into buf 0
  load_lds16(gK, &Ks[0][so]);
  load_lds16(gK + 512, &Ks[0][so + 512]);
  load_lds16(gV, &Vs[0][so]);
  load_lds16(gV + 512, &Vs[0][so + 512]);
  __syncthreads();

#pragma unroll 2
  for (int t = 0; t < 32; ++t) {
    const int cur = t & 1;
    // stage tile t+1 into the other buffer (hidden under this tile's compute)
    if (t < 31) {
      const size_t goff = (size_t)(t + 1) * 4096;
      load_lds16(gK + goff, &Ks[cur ^ 1][so]);
      load_lds16(gK + goff + 512, &Ks[cur ^ 1][so + 512]);
      load_lds16(gV + goff, &Vs[cur ^ 1][so]);
      load_lds16(gV + goff + 512, &Vs[cur ^ 1][so + 512]);
    }

    // K frags for this wave's 32-key slice: subtiles st = kg*2 + kt
    short8 kf[2][2];
#pragma unroll
    for (int kt = 0; kt < 2; ++kt)
#pragma unroll
      for (int kc = 0; kc < 2; ++kc)
        kf[kt][kc] =
            *(const short8*)&Ks[cur][(kg * 2 + kt) * 1024 + kc * 512 + lane * 8];

    // S^T = K_slice . Q^T : s[kt][m], lane holds q-row l16, key = quad*4 + r
    f32x4 s[2][2];
    __builtin_amdgcn_s_setprio(1);
#pragma unroll
    for (int kt = 0; kt < 2; ++kt)
#pragma unroll
      for (int m = 0; m < 2; ++m) {
        f32x4 sc = (f32x4){0.f, 0.f, 0.f, 0.f};
        sc = MFMA32(kf[kt][0], qf[m][0], sc);
        sc = MFMA32(kf[kt][1], qf[m][1], sc);
        s[kt][m] = sc;
      }
    __builtin_amdgcn_s_setprio(0);

    // V frags for this slice (sigma-permuted B-frags, st2 == kg)
    short8 v8[4];
#pragma unroll
    for (int dt = 0; dt < 4; ++dt)
      v8[dt] = *(const short8*)&Vs[cur][(kg * 4 + dt) * 512 + lane * 8];

    // P = exp2(s) packed into sigma-ordered x32 A-frags: e = kt*4 + r
    short8 p8[2];
#pragma unroll
    for (int m = 0; m < 2; ++m) {
      short8 p;
#pragma unroll
      for (int kt = 0; kt < 2; ++kt)
#pragma unroll
        for (int r = 0; r < 4; ++r)
          p[kt * 4 + r] =
              (short)f32_to_bf16_fast(__builtin_amdgcn_exp2f(s[kt][m][r]));
      p8[m] = p;
    }

    // O += P V via MFMA32 (one x32 per (m,dt): k-dim = this wave's 32 keys)
    __builtin_amdgcn_s_setprio(1);
#pragma unroll
    for (int m = 0; m < 2; ++m) {
      o4[m] = MFMA32(p8[m], ones8, o4[m]);
#pragma unroll
      for (int dt = 0; dt < 4; ++dt)
        o[m][dt] = MFMA32(p8[m], v8[dt], o[m][dt]);
    }
    __builtin_amdgcn_s_setprio(0);

    __syncthreads();
  }

  // epilogue: combine k-halves through the dead K/V LDS buffers, then store.
  float* fKs = (float*)&Ks[0][0];   // 4096 floats
  float* fVs = (float*)&Vs[0][0];   // 4096 floats
  if (kg == 1) {
#pragma unroll
    for (int m = 0; m < 2; ++m) {
      *(f32x4*)&fVs[(qg * 2 + m) * 256 + lane * 4] = o4[m];
#pragma unroll
      for (int dt = 0; dt < 4; ++dt)
        *(f32x4*)&fKs[((qg * 2 + m) * 4 + dt) * 256 + lane * 4] = o[m][dt];
    }
  }
  __syncthreads();
  if (kg == 0) {
#pragma unroll
    for (int m = 0; m < 2; ++m) {
      const f32x4 l1 = *(const f32x4*)&fVs[(qg * 2 + m) * 256 + lane * 4];
#pragma unroll
      for (int dt = 0; dt < 4; ++dt)
        o[m][dt] += *(const f32x4*)&fKs[((qg * 2 + m) * 4 + dt) * 256 + lane * 4];
#pragma unroll
      for (int r = 0; r < 4; ++r) {
        const float inv = 1.0f / (o4[m][r] + l1[r]);
        const int row = i0 + m * 16 + quad * 4 + r;
        const size_t obase = (size_t)(ib * 2048 + row) * 1024 + h * 64;
#pragma unroll
        for (int dt = 0; dt < 4; ++dt)
          out[obase + dt * 16 + l16] = f32_to_bf16(o[m][dt][r] * inv);
      }
    }
  }
}

// ---------------- launch ----------------
extern "C" void kernel_launch(void* const* d_in, const int* in_sizes, int n_in,
                              void* d_out, int out_size, void* d_ws, size_t ws_size,
                              hipStream_t stream) {
  const float* x = (const float*)d_in[0];     // [2,2048,1024]
  const float* Wqkv = (const float*)d_in[1];  // [3072,1024]
  const float* Wout = (const float*)d_in[2];  // [1024,1024]
  const float* bout = (const float*)d_in[3];  // [1024]

  uint16_t* xb = (uint16_t*)d_ws;                       // 4096*1024
  uint16_t* wqkvb = xb + (size_t)4096 * 1024;           // 3072*1024
  uint16_t* woutb = wqkvb + (size_t)3072 * 1024;        // 1024*1024
  uint16_t* qh = woutb + (size_t)1024 * 1024;           // 32 heads * 131072
  uint16_t* kh = qh + (size_t)32 * 131072;
  uint16_t* vh = kh + (size_t)32 * 131072;
  uint16_t* attnb = vh + (size_t)32 * 131072;           // 4096*1024

  cvt3_kernel<<<8192, 256, 0, stream>>>(x, Wqkv, Wout, xb, wqkvb, woutb);

  gemm_qkv_kernel<<<dim3(4096 / 128, 3072 / 64), 256, 0, stream>>>(
      xb, wqkvb, qh, kh, vh);

  attn_kernel<<<1024, 256, 0, stream>>>(qh, kh, vh, attnb);

  gemm_out_kernel<<<dim3(4096 / 64, 1024 / 64), 256, 0, stream>>>(
      attnb, woutb, (float*)d_out, bout);
}

// Round 14
// 171.416 us; speedup vs baseline: 1.0970x; 1.0330x over previous
//
#include <hip/hip_runtime.h>
#include <stdint.h>

typedef __attribute__((ext_vector_type(8))) short short8;
typedef __attribute__((ext_vector_type(4))) short bf16x4;
typedef __attribute__((ext_vector_type(4))) float f32x4;
typedef __attribute__((ext_vector_type(4))) unsigned int u32x4;

#define MFMA32(a, b, c) __builtin_amdgcn_mfma_f32_16x16x32_bf16((a), (b), (c), 0, 0, 0)

__device__ __forceinline__ uint16_t f32_to_bf16(float f) {
  union { float f; uint32_t u; } v; v.f = f;
  uint32_t u = v.u;
  u += 0x7FFFu + ((u >> 16) & 1u);   // RTNE
  return (uint16_t)(u >> 16);
}

__device__ __forceinline__ void load_lds16(const uint16_t* g, uint16_t* l) {
  __builtin_amdgcn_global_load_lds(
      (const __attribute__((address_space(1))) uint32_t*)g,
      (__attribute__((address_space(3))) uint32_t*)l, 16, 0, 0);
}

// ---------------- fused f32 -> bf16 conversion (x, Wqkv, Wout) ----------------
__global__ __launch_bounds__(256) void cvt3_kernel(
    const float* __restrict__ x, const float* __restrict__ w1,
    const float* __restrict__ w2, uint16_t* __restrict__ xb,
    uint16_t* __restrict__ w1b, uint16_t* __restrict__ w2b) {
  const int i = blockIdx.x * 256 + threadIdx.x;  // 2,097,152 float4 total
  const float4* src;
  ushort4* dst;
  int off;
  if (i < 1048576) { src = (const float4*)x;  dst = (ushort4*)xb;  off = i; }
  else if (i < 1835008) { src = (const float4*)w1; dst = (ushort4*)w1b; off = i - 1048576; }
  else { src = (const float4*)w2; dst = (ushort4*)w2b; off = i - 1835008; }
  const float4 v = src[off];
  ushort4 o;
  o.x = f32_to_bf16(v.x);
  o.y = f32_to_bf16(v.y);
  o.z = f32_to_bf16(v.z);
  o.w = f32_to_bf16(v.w);
  dst[off] = o;
}

// ---------------- QKV GEMM: 128x64 tile, BK=64, single-buffer serial (R11, proven) ----------------
__global__ __launch_bounds__(256) void gemm_qkv_kernel(
    const uint16_t* __restrict__ A, const uint16_t* __restrict__ Bt,
    uint16_t* __restrict__ Qh, uint16_t* __restrict__ Kh, uint16_t* __restrict__ Vh) {
  __shared__ __align__(16) uint16_t As[128 * 64];   // 16 KB
  __shared__ __align__(16) uint16_t Bs[64 * 64];    // 8 KB
  const int tid = threadIdx.x;
  const int wave = tid >> 6;
  const int lane = tid & 63;
  const int quad = lane >> 4;
  const int l16 = lane & 15;
  const int row0 = blockIdx.x * 128;
  const int col0 = blockIdx.y * 64;
  const int wm = (wave >> 1) * 64;
  const int wn = (wave & 1) * 32;
  const int K = 1024;

  f32x4 acc[4][2];
#pragma unroll
  for (int a = 0; a < 4; ++a)
#pragma unroll
    for (int b = 0; b < 2; ++b) acc[a][b] = (f32x4){0.f, 0.f, 0.f, 0.f};

  // staging: source chunk pre-swizzled (T2 write side); read swizzle cancels it.
  const int swz8 = ((lane & 7) ^ ((lane >> 3) & 7)) * 8;
  const uint16_t* gA = A + (size_t)(row0 + wave * 32 + (lane >> 3)) * K + swz8;
  const uint16_t* gB = Bt + (size_t)(col0 + wave * 16 + (lane >> 3)) * K + swz8;

  for (int k0 = 0; k0 < K; k0 += 64) {
#pragma unroll
    for (int s = 0; s < 4; ++s)
      load_lds16(gA + (size_t)s * 8 * K + k0, &As[(wave * 32 + s * 8) * 64]);
#pragma unroll
    for (int s = 0; s < 2; ++s)
      load_lds16(gB + (size_t)s * 8 * K + k0, &Bs[(wave * 16 + s * 8) * 64]);
    __syncthreads();
#pragma unroll
    for (int ks = 0; ks < 2; ++ks) {
      const int cswz = (((ks * 4 + quad) ^ (l16 & 7)) * 8);
      short8 af[4], bf[2];
#pragma unroll
      for (int mt = 0; mt < 4; ++mt)
        af[mt] = *(const short8*)&As[(wm + mt * 16 + l16) * 64 + cswz];
#pragma unroll
      for (int nt = 0; nt < 2; ++nt)
        bf[nt] = *(const short8*)&Bs[(wn + nt * 16 + l16) * 64 + cswz];
#pragma unroll
      for (int mt = 0; mt < 4; ++mt)
#pragma unroll
        for (int nt = 0; nt < 2; ++nt)
          acc[mt][nt] = MFMA32(af[mt], bf[nt], acc[mt][nt]);
    }
    __syncthreads();
  }

  // epilogue: qkv swizzle (verbatim R9 formulas)
#pragma unroll
  for (int mt = 0; mt < 4; ++mt) {
#pragma unroll
    for (int nt = 0; nt < 2; ++nt) {
      const int col = col0 + wn + nt * 16 + l16;
      const int which = col >> 10;          // 0=q 1=k 2=v (block-uniform, 1024%64==0)
      const int hc = (col & 1023) >> 6;
      const int d = col & 63;
#pragma unroll
      for (int r = 0; r < 4; ++r) {
        const int row = row0 + wm + mt * 16 + quad * 4 + r;
        const float val = acc[mt][nt][r];
        const int b = row >> 11;
        const int nn = row & 2047;
        const size_t hb = (size_t)(b * 16 + hc) * 131072;
        if (which == 0) {
          // fold softmax scale (1/8) and log2(e) into Q
          Qh[hb + (size_t)nn * 64 + d] = f32_to_bf16(val * 0.1803368801111244f);
        } else if (which == 1) {
          const uint16_t bv = f32_to_bf16(val);
          // K: 16x16x32 A-frag order [jt][st][kc][lane=qd*16+j16][e8]
          const int jt = nn >> 6, st = (nn >> 4) & 3, j16 = nn & 15;
          const int kc = d >> 5, qd = (d >> 3) & 3, e = d & 7;
          Kh[hb + jt * 4096 + st * 1024 + kc * 512 + (qd * 16 + j16) * 8 + e] = bv;
        } else {
          const uint16_t bv = f32_to_bf16(val);
          // V: 16x16x32 B-frag, sigma-permuted j (R9):
          const int jt = nn >> 6, jp = nn & 63;
          const int st2 = jp >> 5, j32 = jp & 31;
          const int qv = (j32 >> 2) & 3, e = (j32 >> 4) * 4 + (j32 & 3);
          const int dt = d >> 4, d16 = d & 15;
          Vh[hb + jt * 4096 + (st2 * 4 + dt) * 512 + (qv * 16 + d16) * 8 + e] = bv;
        }
      }
    }
  }
}

// ---------------- output-proj GEMM: 64x64 tile, BK=64, single-buffer serial (R12) ----------------
__global__ __launch_bounds__(256) void gemm_out_kernel(
    const uint16_t* __restrict__ A, const uint16_t* __restrict__ Bt,
    float* __restrict__ Cf, const float* __restrict__ bias) {
  __shared__ __align__(16) uint16_t As[64 * 64];    // 8 KB
  __shared__ __align__(16) uint16_t Bs[64 * 64];    // 8 KB
  const int tid = threadIdx.x;
  const int wave = tid >> 6;
  const int lane = tid & 63;
  const int quad = lane >> 4;
  const int l16 = lane & 15;
  const int row0 = blockIdx.x * 64;
  const int col0 = blockIdx.y * 64;
  const int wm = (wave >> 1) * 32;
  const int wn = (wave & 1) * 32;
  const int K = 1024;
  const int N = 1024;

  f32x4 acc[2][2];
#pragma unroll
  for (int a = 0; a < 2; ++a)
#pragma unroll
    for (int b = 0; b < 2; ++b) acc[a][b] = (f32x4){0.f, 0.f, 0.f, 0.f};

  const int swz8 = ((lane & 7) ^ ((lane >> 3) & 7)) * 8;
  const uint16_t* gA = A + (size_t)(row0 + wave * 16 + (lane >> 3)) * K + swz8;
  const uint16_t* gB = Bt + (size_t)(col0 + wave * 16 + (lane >> 3)) * K + swz8;

  for (int k0 = 0; k0 < K; k0 += 64) {
#pragma unroll
    for (int s = 0; s < 2; ++s) {
      load_lds16(gA + (size_t)s * 8 * K + k0, &As[(wave * 16 + s * 8) * 64]);
      load_lds16(gB + (size_t)s * 8 * K + k0, &Bs[(wave * 16 + s * 8) * 64]);
    }
    __syncthreads();
#pragma unroll
    for (int ks = 0; ks < 2; ++ks) {
      const int cswz = (((ks * 4 + quad) ^ (l16 & 7)) * 8);
      short8 af[2], bf[2];
#pragma unroll
      for (int mt = 0; mt < 2; ++mt)
        af[mt] = *(const short8*)&As[(wm + mt * 16 + l16) * 64 + cswz];
#pragma unroll
      for (int nt = 0; nt < 2; ++nt)
        bf[nt] = *(const short8*)&Bs[(wn + nt * 16 + l16) * 64 + cswz];
#pragma unroll
      for (int mt = 0; mt < 2; ++mt)
#pragma unroll
        for (int nt = 0; nt < 2; ++nt)
          acc[mt][nt] = MFMA32(af[mt], bf[nt], acc[mt][nt]);
    }
    __syncthreads();
  }

#pragma unroll
  for (int mt = 0; mt < 2; ++mt) {
#pragma unroll
    for (int nt = 0; nt < 2; ++nt) {
      const int col = col0 + wn + nt * 16 + l16;
#pragma unroll
      for (int r = 0; r < 4; ++r) {
        const int row = row0 + wm + mt * 16 + quad * 4 + r;
        Cf[(size_t)row * N + col] = acc[mt][nt][r] + bias[col];
      }
    }
  }
}

// ---------------- flash attention: 2q x 2k wave-split, cvt_pk P-packing ----------------
// R13 post-mortem: halving ds_reads was NULL -> LDS not critical path. Per-pipe
// arithmetic: VALU is tallest (16 exp2 + ~48 insts of bit-trick bf16 packing
// per tile per wave). R14: P-packing via v_cvt_pk_bf16_f32 (T12 primitive,
// proven inside attn m214v22) -- 8 asm insts replace ~48 VALU insts; builds the
// sigma-frag short8 words directly (elem e=kt*4+r -> word kt*2+(r>>1), low=even
// r). Rounding: RTNE (was round-half-up) on P only. m240 risk (asm hurts when
// compiler handled it) pre-committed: regression -> revert.
__global__ __launch_bounds__(256, 4) void attn_kernel(
    const uint16_t* __restrict__ Qh, const uint16_t* __restrict__ Kh,
    const uint16_t* __restrict__ Vh, uint16_t* __restrict__ out) {
  __shared__ __align__(16) uint16_t Ks[2][4096];
  __shared__ __align__(16) uint16_t Vs[2][4096];
  const int tid = threadIdx.x;
  const int wave = tid >> 6;
  const int lane = tid & 63;
  const int quad = lane >> 4;
  const int l16 = lane & 15;
  const int qg = wave >> 1;         // q-group: 32 rows
  const int kg = wave & 1;          // k-group: 32 keys of each 64-key tile
  const int bx = blockIdx.x;
  // bx = g*8 + xcd ; g = it + 32*hhi + 64*ib ; h = hhi*8 + xcd
  const int xcd = bx & 7;
  const int g = bx >> 3;
  const int it = g & 31;            // 32 i-tiles of 64 rows
  const int h = ((g >> 5) & 1) * 8 + xcd;
  const int ib = g >> 6;
  const int i0 = it * 64 + qg * 32;
  const size_t hb = (size_t)(ib * 16 + h) * 131072;

  // Q fragments for 32 rows (B-operand of S^T MFMA): lane l16 = q-row
  short8 qf[2][2];
#pragma unroll
  for (int m = 0; m < 2; ++m)
#pragma unroll
    for (int kc = 0; kc < 2; ++kc)
      qf[m][kc] = *(const short8*)(Qh + hb + (size_t)(i0 + m * 16 + l16) * 64 +
                                   kc * 32 + quad * 8);

  f32x4 o[2][4], o4[2];
#pragma unroll
  for (int m = 0; m < 2; ++m) {
    o4[m] = (f32x4){0.f, 0.f, 0.f, 0.f};
#pragma unroll
    for (int t = 0; t < 4; ++t) o[m][t] = (f32x4){0.f, 0.f, 0.f, 0.f};
  }

  const short8 ones8 = {(short)0x3F80, (short)0x3F80, (short)0x3F80, (short)0x3F80,
                        (short)0x3F80, (short)0x3F80, (short)0x3F80, (short)0x3F80};

  // staging: this wave stages elems [wave*1024, wave*1024+1024) of each tile
  const uint16_t* gK = Kh + hb + wave * 1024 + lane * 8;
  const uint16_t* gV = Vh + hb + wave * 1024 + lane * 8;
  const int so = wave * 1024;

  // prologue: stage tile 0 into buf 0
  load_lds16(gK, &Ks[0][so]);
  load_lds16(gK + 512, &Ks[0][so + 512]);
  load_lds16(gV, &Vs[0][so]);
  load_lds16(gV + 512, &Vs[0][so + 512]);
  __syncthreads();

#pragma unroll 2
  for (int t = 0; t < 32; ++t) {
    const int cur = t & 1;
    // stage tile t+1 into the other buffer (hidden under this tile's compute)
    if (t < 31) {
      const size_t goff = (size_t)(t + 1) * 4096;
      load_lds16(gK + goff, &Ks[cur ^ 1][so]);
      load_lds16(gK + goff + 512, &Ks[cur ^ 1][so + 512]);
      load_lds16(gV + goff, &Vs[cur ^ 1][so]);
      load_lds16(gV + goff + 512, &Vs[cur ^ 1][so + 512]);
    }

    // K frags for this wave's 32-key slice: subtiles st = kg*2 + kt
    short8 kf[2][2];
#pragma unroll
    for (int kt = 0; kt < 2; ++kt)
#pragma unroll
      for (int kc = 0; kc < 2; ++kc)
        kf[kt][kc] =
            *(const short8*)&Ks[cur][(kg * 2 + kt) * 1024 + kc * 512 + lane * 8];

    // S^T = K_slice . Q^T : s[kt][m], lane holds q-row l16, key = quad*4 + r
    f32x4 s[2][2];
    __builtin_amdgcn_s_setprio(1);
#pragma unroll
    for (int kt = 0; kt < 2; ++kt)
#pragma unroll
      for (int m = 0; m < 2; ++m) {
        f32x4 sc = (f32x4){0.f, 0.f, 0.f, 0.f};
        sc = MFMA32(kf[kt][0], qf[m][0], sc);
        sc = MFMA32(kf[kt][1], qf[m][1], sc);
        s[kt][m] = sc;
      }
    __builtin_amdgcn_s_setprio(0);

    // V frags for this slice (sigma-permuted B-frags, st2 == kg)
    short8 v8[4];
#pragma unroll
    for (int dt = 0; dt < 4; ++dt)
      v8[dt] = *(const short8*)&Vs[cur][(kg * 4 + dt) * 512 + lane * 8];

    // P = exp2(s) packed into sigma-ordered x32 A-frags via v_cvt_pk_bf16_f32:
    // elem e = kt*4 + r -> word kt*2 + (r>>1); low16 = even r, high16 = odd r.
    short8 p8[2];
#pragma unroll
    for (int m = 0; m < 2; ++m) {
      u32x4 pw;
#pragma unroll
      for (int kt = 0; kt < 2; ++kt)
#pragma unroll
        for (int rp = 0; rp < 2; ++rp) {
          const float lo = __builtin_amdgcn_exp2f(s[kt][m][rp * 2 + 0]);
          const float hi = __builtin_amdgcn_exp2f(s[kt][m][rp * 2 + 1]);
          unsigned int w;
          asm("v_cvt_pk_bf16_f32 %0, %1, %2" : "=v"(w) : "v"(lo), "v"(hi));
          pw[kt * 2 + rp] = w;
        }
      p8[m] = *(const short8*)&pw;
    }

    // O += P V via MFMA32 (one x32 per (m,dt): k-dim = this wave's 32 keys)
    __builtin_amdgcn_s_setprio(1);
#pragma unroll
    for (int m = 0; m < 2; ++m) {
      o4[m] = MFMA32(p8[m], ones8, o4[m]);
#pragma unroll
      for (int dt = 0; dt < 4; ++dt)
        o[m][dt] = MFMA32(p8[m], v8[dt], o[m][dt]);
    }
    __builtin_amdgcn_s_setprio(0);

    __syncthreads();
  }

  // epilogue: combine k-halves through the dead K/V LDS buffers, then store.
  float* fKs = (float*)&Ks[0][0];   // 4096 floats
  float* fVs = (float*)&Vs[0][0];   // 4096 floats
  if (kg == 1) {
#pragma unroll
    for (int m = 0; m < 2; ++m) {
      *(f32x4*)&fVs[(qg * 2 + m) * 256 + lane * 4] = o4[m];
#pragma unroll
      for (int dt = 0; dt < 4; ++dt)
        *(f32x4*)&fKs[((qg * 2 + m) * 4 + dt) * 256 + lane * 4] = o[m][dt];
    }
  }
  __syncthreads();
  if (kg == 0) {
#pragma unroll
    for (int m = 0; m < 2; ++m) {
      const f32x4 l1 = *(const f32x4*)&fVs[(qg * 2 + m) * 256 + lane * 4];
#pragma unroll
      for (int dt = 0; dt < 4; ++dt)
        o[m][dt] += *(const f32x4*)&fKs[((qg * 2 + m) * 4 + dt) * 256 + lane * 4];
#pragma unroll
      for (int r = 0; r < 4; ++r) {
        const float inv = 1.0f / (o4[m][r] + l1[r]);
        const int row = i0 + m * 16 + quad * 4 + r;
        const size_t obase = (size_t)(ib * 2048 + row) * 1024 + h * 64;
#pragma unroll
        for (int dt = 0; dt < 4; ++dt)
          out[obase + dt * 16 + l16] = f32_to_bf16(o[m][dt][r] * inv);
      }
    }
  }
}

// ---------------- launch ----------------
extern "C" void kernel_launch(void* const* d_in, const int* in_sizes, int n_in,
                              void* d_out, int out_size, void* d_ws, size_t ws_size,
                              hipStream_t stream) {
  const float* x = (const float*)d_in[0];     // [2,2048,1024]
  const float* Wqkv = (const float*)d_in[1];  // [3072,1024]
  const float* Wout = (const float*)d_in[2];  // [1024,1024]
  const float* bout = (const float*)d_in[3];  // [1024]

  uint16_t* xb = (uint16_t*)d_ws;                       // 4096*1024
  uint16_t* wqkvb = xb + (size_t)4096 * 1024;           // 3072*1024
  uint16_t* woutb = wqkvb + (size_t)3072 * 1024;        // 1024*1024
  uint16_t* qh = woutb + (size_t)1024 * 1024;           // 32 heads * 131072
  uint16_t* kh = qh + (size_t)32 * 131072;
  uint16_t* vh = kh + (size_t)32 * 131072;
  uint16_t* attnb = vh + (size_t)32 * 131072;           // 4096*1024

  cvt3_kernel<<<8192, 256, 0, stream>>>(x, Wqkv, Wout, xb, wqkvb, woutb);

  gemm_qkv_kernel<<<dim3(4096 / 128, 3072 / 64), 256, 0, stream>>>(
      xb, wqkvb, qh, kh, vh);

  attn_kernel<<<1024, 256, 0, stream>>>(qh, kh, vh, attnb);

  gemm_out_kernel<<<dim3(4096 / 64, 1024 / 64), 256, 0, stream>>>(
      attnb, woutb, (float*)d_out, bout);
}